// Round 15
// baseline (20.666 us; speedup 1.0000x reference)
//
#include <hip/hip_runtime.h>

// Problem constants (fixed by setup_inputs): BS=2, NCAM=3, N=64, S=256
constexpr int S_IMG = 256;
constexpr int NPT   = 64;
constexpr int BC    = 6;      // BS*NCAM
constexpr int NCAM_ = 3;

typedef float vf2 __attribute__((ext_vector_type(2)));
typedef float vf4 __attribute__((ext_vector_type(4)));

__device__ __forceinline__ float blob_eval(float u, float e) {
    // exp(-(u^e)) ; u^e = exp2(e*log2(u)) ; exp(-v) = exp2(-log2e*v)
    // u==0: log2->-inf, exp2->0, result exp2(-0)=1 == reference limit.
    // u large: e*log2(u) big -> exp2 huge -> exp2(-1.44*huge) == +0.
    float v = exp2f(e * __log2f(u));
    return exp2f(-1.4426950408889634f * v);
}

// R15: max-occupancy variant. 1536 blocks x 256 threads (8 blocks/CU
// resident = 2048 threads/CU = 8 waves/SIMD, vs R14's 6). Block owns one
// image row (bit-reversed scatter); wave w (0..3) sweeps n in [w*16,w*16+16);
// lane owns 4 px -> float4 1KB wave-stores. Mask partials merged 4-way via
// LDS. Early-out: whole-wave u >= Rn -> write zeros, skip transcendentals.
__global__ __launch_bounds__(256) void render_fused(
    const float* __restrict__ points,       // (BC,N,2)
    const float* __restrict__ sigmas,       // (BS,N)
    const float* __restrict__ exponents,    // (BS,N)
    const float* __restrict__ intensities,  // (BS,N)
    const float* __restrict__ cam_sig,      // (BS,NCAM)
    const float* __restrict__ cam_exp,      // (BS,NCAM)
    const float* __restrict__ cam_int,      // (BS,NCAM)
    float* __restrict__ masks,              // (BC,S,S)
    float* __restrict__ blobs)              // (BC,N,S,S)
{
    const int blk = blockIdx.x;             // 0..1535
    const int bc  = blk >> 8;
    // bit-reverse the 8-bit row index: adjacent y -> distant blocks
    const int y   = (int)(__brev((unsigned)(blk & 255)) >> 24);
    const int b   = bc / NCAM_;
    const int t   = threadIdx.x;            // 0..255

    // packed params: sP[n] = (px, py, k, Rn) ; sQ[n] = (e, intensity)
    __shared__ vf4 sP[NPT];
    __shared__ vf2 sQ[NPT];
    __shared__ vf4 sM[3][64];               // mask partials, waves 0..2
    if (t < NPT) {
        float px = points[(bc * NPT + t) * 2 + 0];
        float py = points[(bc * NPT + t) * 2 + 1];
        px = fminf(fmaxf((px - 128.0f) * (1.0f / 128.0f), -1.0f), 1.0f);
        py = fminf(fmaxf((py - 128.0f) * (1.0f / 128.0f), -1.0f), 1.0f);
        float sg = sigmas[b * NPT + t] * cam_sig[bc];
        float e  = exponents[b * NPT + t] * cam_exp[bc];
        vf4 P;
        P.x = px;
        P.y = py;
        P.z = 1.0f / (2.0f * sg * sg);
        P.w = exp2f(3.2034f / e);           // u >= Rn => blob <= 1e-4
        sP[t] = P;
        vf2 Q;
        Q.x = e;
        Q.y = intensities[b * NPT + t] * cam_int[bc];
        sQ[t] = Q;
    }
    __syncthreads();

    const int w     = t >> 6;               // wave 0..3: n in [w*16, w*16+16)
    const int lane  = t & 63;
    const int nbase = w << 4;
    const int x     = lane << 2;            // 4 px/thread

    const float step = 2.0f / 255.0f;       // linspace(-1,1,256) step
    const float gy   = fmaf((float)y, step, -1.0f);
    float gx[4];
    #pragma unroll
    for (int j = 0; j < 4; ++j) gx[j] = fmaf((float)(x + j), step, -1.0f);

    float m0 = 0.0f, m1 = 0.0f, m2 = 0.0f, m3 = 0.0f;
    float* bp = blobs + ((size_t)(bc * NPT + nbase) << 16)
                      + ((size_t)y << 8) + x;
    const size_t nstride = (size_t)S_IMG * S_IMG;

    #pragma unroll 4
    for (int i = 0; i < 16; ++i) {
        vf4 P = sP[nbase + i];              // one ds_read_b128
        float dyv  = gy - P.y;
        float kdy2 = P.z * dyv * dyv;
        float dx0 = gx[0] - P.x, dx1 = gx[1] - P.x;
        float dx2 = gx[2] - P.x, dx3 = gx[3] - P.x;
        float u0 = fmaf(P.z * dx0, dx0, kdy2);
        float u1 = fmaf(P.z * dx1, dx1, kdy2);
        float u2 = fmaf(P.z * dx2, dx2, kdy2);
        float u3 = fmaf(P.z * dx3, dx3, kdy2);
        vf4 o; o.x = 0.0f; o.y = 0.0f; o.z = 0.0f; o.w = 0.0f;
        float umin = fminf(fminf(u0, u1), fminf(u2, u3));
        if (umin < P.w) {                   // wave-level execz skip
            vf2 Q = sQ[nbase + i];
            o.x = blob_eval(u0, Q.x);       // self-zeroes for far px
            o.y = blob_eval(u1, Q.x);
            o.z = blob_eval(u2, Q.x);
            o.w = blob_eval(u3, Q.x);
            m0 = fmaxf(m0, o.x * Q.y);
            m1 = fmaxf(m1, o.y * Q.y);
            m2 = fmaxf(m2, o.z * Q.y);
            m3 = fmaxf(m3, o.w * Q.y);
        }
        *reinterpret_cast<vf4*>(bp + i * nstride) = o;  // 1KB/wave store
    }

    // merge the four waves' mask partials via LDS; wave 3 stores.
    if (w < 3) {
        vf4 mv; mv.x = m0; mv.y = m1; mv.z = m2; mv.w = m3;
        sM[w][lane] = mv;
    }
    __syncthreads();
    if (w == 3) {
        vf4 p0 = sM[0][lane];
        vf4 p1 = sM[1][lane];
        vf4 p2 = sM[2][lane];
        vf4 mm;
        mm.x = fminf(fmaxf(fmaxf(m0, p0.x), fmaxf(p1.x, p2.x)), 1.0f);
        mm.y = fminf(fmaxf(fmaxf(m1, p0.y), fmaxf(p1.y, p2.y)), 1.0f);
        mm.z = fminf(fmaxf(fmaxf(m2, p0.z), fmaxf(p1.z, p2.z)), 1.0f);
        mm.w = fminf(fmaxf(fmaxf(m3, p0.w), fmaxf(p1.w, p2.w)), 1.0f);
        *reinterpret_cast<vf4*>(masks + ((size_t)bc << 16)
                                      + ((size_t)y << 8) + x) = mm;
    }
}

extern "C" void kernel_launch(void* const* d_in, const int* in_sizes, int n_in,
                              void* d_out, int out_size, void* d_ws, size_t ws_size,
                              hipStream_t stream) {
    const float* points      = (const float*)d_in[0];
    const float* sigmas      = (const float*)d_in[1];
    const float* exponents   = (const float*)d_in[2];
    const float* intensities = (const float*)d_in[3];
    const float* cam_sig     = (const float*)d_in[4];
    const float* cam_exp     = (const float*)d_in[5];
    const float* cam_int     = (const float*)d_in[6];
    // d_in[7] = image_size (256), fixed by problem shape — hardcoded.

    float* masks = (float*)d_out;                                // BC*S*S
    float* blobs = (float*)d_out + (size_t)BC * S_IMG * S_IMG;   // BC*N*S*S

    dim3 grid(BC * S_IMG);   // 1536: one row per block
    dim3 block(256);
    render_fused<<<grid, block, 0, stream>>>(
        points, sigmas, exponents, intensities, cam_sig, cam_exp, cam_int,
        masks, blobs);
}

// Round 16
// 20.156 us; speedup vs baseline: 1.0253x; 1.0253x over previous
//
#include <hip/hip_runtime.h>

// Problem constants (fixed by setup_inputs): BS=2, NCAM=3, N=64, S=256
constexpr int S_IMG = 256;
constexpr int NPT   = 64;
constexpr int BC    = 6;      // BS*NCAM
constexpr int NCAM_ = 3;

typedef float vf2 __attribute__((ext_vector_type(2)));
typedef float vf4 __attribute__((ext_vector_type(4)));

__device__ __forceinline__ float blob_eval(float u, float e) {
    // exp(-(u^e)) ; u^e = exp2(e*log2(u)) ; exp(-v) = exp2(-log2e*v)
    // u==0: log2->-inf, exp2->0, result exp2(-0)=1 == reference limit.
    // u large: e*log2(u) big -> exp2 huge -> exp2(-1.44*huge) == +0.
    float v = exp2f(e * __log2f(u));
    return exp2f(-1.4426950408889634f * v);
}

// FINAL (= R14, best measured: 20.23us). 768 blocks x 512 threads,
// 6 waves/SIMD. Block owns a row-pair (bc, y0..y0+1) with bit-reversed
// row-pair assignment (tail-scatter, -4%). Threads split 4-way over n:
// quarter q=t>>7 sweeps 16 points over the 512 px (4 px/thread -> float4
// 1KB wave-stores). Early-out Rn cutoff skips the 3-transcendental chain
// wave-wide for far pixels (-11%). Mask partials merged 4-way via LDS.
// Measured 5.05 TB/s effective vs 6.3-6.9 TB/s fill ceiling: write-BW
// bound including fixed launch/ramp overhead.
__global__ __launch_bounds__(512) void render_fused(
    const float* __restrict__ points,       // (BC,N,2)
    const float* __restrict__ sigmas,       // (BS,N)
    const float* __restrict__ exponents,    // (BS,N)
    const float* __restrict__ intensities,  // (BS,N)
    const float* __restrict__ cam_sig,      // (BS,NCAM)
    const float* __restrict__ cam_exp,      // (BS,NCAM)
    const float* __restrict__ cam_int,      // (BS,NCAM)
    float* __restrict__ masks,              // (BC,S,S)
    float* __restrict__ blobs)              // (BC,N,S,S)
{
    const int blk = blockIdx.x;             // 0..767
    const int bc  = blk >> 7;
    // bit-reverse the 7-bit row-pair index: adjacent y -> distant blocks
    const int rp  = (int)(__brev((unsigned)(blk & 127)) >> 25);
    const int y0  = rp << 1;
    const int b   = bc / NCAM_;
    const int t   = threadIdx.x;            // 0..511

    // packed params: sP[n] = (px, py, k, Rn) ; sQ[n] = (e, intensity)
    __shared__ vf4 sP[NPT];
    __shared__ vf2 sQ[NPT];
    __shared__ vf4 sM[3][128];              // mask partials, quarters 0..2
    if (t < NPT) {
        float px = points[(bc * NPT + t) * 2 + 0];
        float py = points[(bc * NPT + t) * 2 + 1];
        px = fminf(fmaxf((px - 128.0f) * (1.0f / 128.0f), -1.0f), 1.0f);
        py = fminf(fmaxf((py - 128.0f) * (1.0f / 128.0f), -1.0f), 1.0f);
        float sg = sigmas[b * NPT + t] * cam_sig[bc];
        float e  = exponents[b * NPT + t] * cam_exp[bc];
        vf4 P;
        P.x = px;
        P.y = py;
        P.z = 1.0f / (2.0f * sg * sg);
        P.w = exp2f(3.2034f / e);           // u >= Rn => blob <= 1e-4
        sP[t] = P;
        vf2 Q;
        Q.x = e;
        Q.y = intensities[b * NPT + t] * cam_int[bc];
        sQ[t] = Q;
    }
    __syncthreads();

    const int q     = t >> 7;               // quarter 0..3: n in [q*16,q*16+16)
    const int tt    = t & 127;
    const int nbase = q << 4;
    const int lin   = tt << 2;              // 4 px/thread
    const int y     = y0 + (lin >> 8);
    const int x     = lin & 255;

    const float step = 2.0f / 255.0f;       // linspace(-1,1,256) step
    const float gy   = fmaf((float)y, step, -1.0f);
    float gx[4];
    #pragma unroll
    for (int j = 0; j < 4; ++j) gx[j] = fmaf((float)(x + j), step, -1.0f);

    float m0 = 0.0f, m1 = 0.0f, m2 = 0.0f, m3 = 0.0f;
    float* bp = blobs + ((size_t)(bc * NPT + nbase) << 16)
                      + ((size_t)y << 8) + x;
    const size_t nstride = (size_t)S_IMG * S_IMG;

    #pragma unroll 4
    for (int i = 0; i < 16; ++i) {
        vf4 P = sP[nbase + i];              // one ds_read_b128
        float dyv  = gy - P.y;
        float kdy2 = P.z * dyv * dyv;
        float dx0 = gx[0] - P.x, dx1 = gx[1] - P.x;
        float dx2 = gx[2] - P.x, dx3 = gx[3] - P.x;
        float u0 = fmaf(P.z * dx0, dx0, kdy2);
        float u1 = fmaf(P.z * dx1, dx1, kdy2);
        float u2 = fmaf(P.z * dx2, dx2, kdy2);
        float u3 = fmaf(P.z * dx3, dx3, kdy2);
        vf4 o; o.x = 0.0f; o.y = 0.0f; o.z = 0.0f; o.w = 0.0f;
        float umin = fminf(fminf(u0, u1), fminf(u2, u3));
        if (umin < P.w) {                   // wave-level execz skip
            vf2 Q = sQ[nbase + i];
            o.x = blob_eval(u0, Q.x);       // self-zeroes for far px
            o.y = blob_eval(u1, Q.x);
            o.z = blob_eval(u2, Q.x);
            o.w = blob_eval(u3, Q.x);
            m0 = fmaxf(m0, o.x * Q.y);
            m1 = fmaxf(m1, o.y * Q.y);
            m2 = fmaxf(m2, o.z * Q.y);
            m3 = fmaxf(m3, o.w * Q.y);
        }
        *reinterpret_cast<vf4*>(bp + i * nstride) = o;  // 1KB/wave store
    }

    // merge the four quarters' mask partials via LDS; quarter 3 stores.
    if (q < 3) {
        vf4 mv; mv.x = m0; mv.y = m1; mv.z = m2; mv.w = m3;
        sM[q][tt] = mv;
    }
    __syncthreads();
    if (q == 3) {
        vf4 p0 = sM[0][tt];
        vf4 p1 = sM[1][tt];
        vf4 p2 = sM[2][tt];
        vf4 mm;
        mm.x = fminf(fmaxf(fmaxf(m0, p0.x), fmaxf(p1.x, p2.x)), 1.0f);
        mm.y = fminf(fmaxf(fmaxf(m1, p0.y), fmaxf(p1.y, p2.y)), 1.0f);
        mm.z = fminf(fmaxf(fmaxf(m2, p0.z), fmaxf(p1.z, p2.z)), 1.0f);
        mm.w = fminf(fmaxf(fmaxf(m3, p0.w), fmaxf(p1.w, p2.w)), 1.0f);
        *reinterpret_cast<vf4*>(masks + ((size_t)bc << 16)
                                      + ((size_t)y << 8) + x) = mm;
    }
}

extern "C" void kernel_launch(void* const* d_in, const int* in_sizes, int n_in,
                              void* d_out, int out_size, void* d_ws, size_t ws_size,
                              hipStream_t stream) {
    const float* points      = (const float*)d_in[0];
    const float* sigmas      = (const float*)d_in[1];
    const float* exponents   = (const float*)d_in[2];
    const float* intensities = (const float*)d_in[3];
    const float* cam_sig     = (const float*)d_in[4];
    const float* cam_exp     = (const float*)d_in[5];
    const float* cam_int     = (const float*)d_in[6];
    // d_in[7] = image_size (256), fixed by problem shape — hardcoded.

    float* masks = (float*)d_out;                                // BC*S*S
    float* blobs = (float*)d_out + (size_t)BC * S_IMG * S_IMG;   // BC*N*S*S

    dim3 grid(BC * (S_IMG / 2));   // 768
    dim3 block(512);
    render_fused<<<grid, block, 0, stream>>>(
        points, sigmas, exponents, intensities, cam_sig, cam_exp, cam_int,
        masks, blobs);
}